// Round 1
// baseline (126.894 us; speedup 1.0000x reference)
//
#include <hip/hip_runtime.h>
#include <hip/hip_bf16.h>
#include <math.h>

#define HID 64
#define TSEQ 96
#define NOUT 96
#define NIN 5
#define FLATN (TSEQ * NOUT)   // 9216

__device__ __forceinline__ float fast_sigmoid(float x) {
    return 1.0f / (1.0f + __expf(-x));
}

__device__ __forceinline__ float fast_tanh(float x) {
    float ax = fabsf(x);
    float e = __expf(-2.0f * ax);
    float t = (1.0f - e) / (1.0f + e);
    return copysignf(t, x);
}

// Kernel 1: full LSTM (96 sequential steps) + linear1, single block of 256 threads.
// Thread tid owns gate row tid (0..255). W_hh row lives in registers.
__global__ __launch_bounds__(256) void lstm_fused_kernel(
    const float* __restrict__ x,     // (T, 5)
    const float* __restrict__ h0,    // (64)
    const float* __restrict__ c0,    // (64)
    const float* __restrict__ Wih,   // (256, 5)
    const float* __restrict__ Whh,   // (256, 64)
    const float* __restrict__ bih,   // (256)
    const float* __restrict__ bhh,   // (256)
    const float* __restrict__ W1,    // (96, 64)
    const float* __restrict__ b1,    // (96)
    float* __restrict__ flat_out)    // (9216) -> workspace
{
    __shared__ float h_s[HID];
    __shared__ float c_s[HID];
    __shared__ float gates[4 * HID];
    __shared__ float x_s[TSEQ * NIN];
    __shared__ float hseq[TSEQ][HID];

    const int tid = threadIdx.x;

    // Stage x into LDS
    for (int i = tid; i < TSEQ * NIN; i += 256) x_s[i] = x[i];
    if (tid < HID) {
        h_s[tid] = h0[tid];
        c_s[tid] = c0[tid];
    }

    // Per-thread weights in registers
    float w[HID];
#pragma unroll
    for (int j = 0; j < HID; ++j) w[j] = Whh[tid * HID + j];
    float wi[NIN];
#pragma unroll
    for (int i = 0; i < NIN; ++i) wi[i] = Wih[tid * NIN + i];
    const float bias = bih[tid] + bhh[tid];

    __syncthreads();

    for (int t = 0; t < TSEQ; ++t) {
        const float* xt = &x_s[t * NIN];
        // 4-way split accumulators to break the FMA dependency chain
        float a0 = bias, a1 = 0.f, a2 = 0.f, a3 = 0.f;
        a0 += wi[0] * xt[0];
        a1 += wi[1] * xt[1];
        a2 += wi[2] * xt[2];
        a3 += wi[3] * xt[3];
        a0 += wi[4] * xt[4];
#pragma unroll
        for (int j = 0; j < HID; j += 4) {
            a0 += w[j + 0] * h_s[j + 0];
            a1 += w[j + 1] * h_s[j + 1];
            a2 += w[j + 2] * h_s[j + 2];
            a3 += w[j + 3] * h_s[j + 3];
        }
        const float pre = (a0 + a1) + (a2 + a3);

        // Gate order: rows [0,64)=i, [64,128)=f, [128,192)=g, [192,256)=o
        // Waves 0,1,3 take sigmoid; wave 2 takes tanh -> wave-uniform branch.
        float act;
        if (tid >= 2 * HID && tid < 3 * HID) {
            act = fast_tanh(pre);
        } else {
            act = fast_sigmoid(pre);
        }
        gates[tid] = act;
        __syncthreads();

        if (tid < HID) {
            const float ig = gates[tid];
            const float fg = gates[HID + tid];
            const float gg = gates[2 * HID + tid];
            const float og = gates[3 * HID + tid];
            const float c_new = fg * c_s[tid] + ig * gg;
            const float h_new = og * fast_tanh(c_new);
            c_s[tid] = c_new;
            h_s[tid] = h_new;
            hseq[t][tid] = h_new;
        }
        __syncthreads();
    }

    // linear1: flat[t*96 + k] = b1[k] + W1[k,:] . hseq[t,:]
    for (int idx = tid; idx < FLATN; idx += 256) {
        const int t = idx / NOUT;
        const int k = idx - t * NOUT;
        const float* w1r = &W1[k * HID];
        float s0 = 0.f, s1 = 0.f, s2 = 0.f, s3 = 0.f;
#pragma unroll
        for (int j = 0; j < HID; j += 4) {
            s0 += w1r[j + 0] * hseq[t][j + 0];
            s1 += w1r[j + 1] * hseq[t][j + 1];
            s2 += w1r[j + 2] * hseq[t][j + 2];
            s3 += w1r[j + 3] * hseq[t][j + 3];
        }
        flat_out[idx] = b1[k] + ((s0 + s1) + (s2 + s3));
    }
}

// Kernel 2: out[o] = b2[o] + W2[o,:] . flat   (96 blocks, one output each)
__global__ __launch_bounds__(256) void gemv_final_kernel(
    const float* __restrict__ W2,    // (96, 9216)
    const float* __restrict__ b2,    // (96)
    const float* __restrict__ flat,  // (9216)
    float* __restrict__ out)         // (96)
{
    const int o = blockIdx.x;
    const int tid = threadIdx.x;
    const float* __restrict__ row = &W2[o * FLATN];

    float s = 0.f;
#pragma unroll 4
    for (int j = tid; j < FLATN; j += 256) {
        s += row[j] * flat[j];
    }

    // wave (64-lane) reduction
#pragma unroll
    for (int off = 32; off > 0; off >>= 1) s += __shfl_down(s, off, 64);

    __shared__ float partial[4];
    if ((tid & 63) == 0) partial[tid >> 6] = s;
    __syncthreads();
    if (tid == 0) {
        out[o] = b2[o] + ((partial[0] + partial[1]) + (partial[2] + partial[3]));
    }
}

extern "C" void kernel_launch(void* const* d_in, const int* in_sizes, int n_in,
                              void* d_out, int out_size, void* d_ws, size_t ws_size,
                              hipStream_t stream) {
    const float* x   = (const float*)d_in[0];   // (1, 96, 5)
    const float* h0  = (const float*)d_in[1];   // (1, 1, 64)
    const float* c0  = (const float*)d_in[2];   // (1, 1, 64)
    const float* Wih = (const float*)d_in[3];   // (256, 5)
    const float* Whh = (const float*)d_in[4];   // (256, 64)
    const float* bih = (const float*)d_in[5];   // (256)
    const float* bhh = (const float*)d_in[6];   // (256)
    const float* W1  = (const float*)d_in[7];   // (96, 64)
    const float* b1  = (const float*)d_in[8];   // (96)
    const float* W2  = (const float*)d_in[9];   // (96, 9216)
    const float* b2  = (const float*)d_in[10];  // (96)

    float* out  = (float*)d_out;                // (96)
    float* flat = (float*)d_ws;                 // 9216 floats scratch

    lstm_fused_kernel<<<1, 256, 0, stream>>>(x, h0, c0, Wih, Whh, bih, bhh, W1, b1, flat);
    gemv_final_kernel<<<NOUT, 256, 0, stream>>>(W2, b2, flat, out);
}

// Round 2
// 93.507 us; speedup vs baseline: 1.3571x; 1.3571x over previous
//
#include <hip/hip_runtime.h>
#include <hip/hip_bf16.h>
#include <math.h>

#define HID 64
#define TSEQ 96
#define NOUT 96
#define NIN 5
#define FLATN (TSEQ * NOUT)   // 9216

__device__ __forceinline__ float fast_sigmoid(float x) {
    return 1.0f / (1.0f + __expf(-x));
}

__device__ __forceinline__ float fast_tanh(float x) {
    float ax = fabsf(x);
    float e = __expf(-2.0f * ax);
    float t = (1.0f - e) / (1.0f + e);
    return copysignf(t, x);
}

// Broadcast lane l's value of v to all lanes via v_readlane -> SGPR.
__device__ __forceinline__ float bcast(float v, int l) {
    return __uint_as_float(__builtin_amdgcn_readlane(__float_as_uint(v), l));
}

// One block of 256 threads = 4 waves. Wave g owns gate rows [g*64, g*64+64).
// Each thread keeps its W_hh row (64 floats) in VGPRs. h and c live
// lane-distributed in registers, replicated in every wave.
__global__ __launch_bounds__(256, 1) void lstm_fused(
    const float* __restrict__ x,     // (96, 5)
    const float* __restrict__ h0,    // (64)
    const float* __restrict__ c0,    // (64)
    const float* __restrict__ Wih,   // (256, 5)
    const float* __restrict__ Whh,   // (256, 64)
    const float* __restrict__ bih,   // (256)
    const float* __restrict__ bhh,   // (256)
    const float* __restrict__ W1,    // (96, 64)
    const float* __restrict__ b1,    // (96)
    float* __restrict__ flat_out)    // (9216) workspace
{
    __shared__ float x_s[TSEQ * NIN];        // 1.9 KB
    __shared__ float g_s[2][4 * HID];        // 2 KB, double-buffered gates
    __shared__ float hseq[TSEQ][HID];        // 24.6 KB

    const int tid  = threadIdx.x;
    const int lane = tid & 63;
    const int wv   = tid >> 6;     // 0..3 = gate index (i, f, g, o)
    const int row  = tid;          // gate row this thread owns

    for (int i = tid; i < TSEQ * NIN; i += 256) x_s[i] = x[i];

    // W_hh row in registers (guaranteed by __launch_bounds__(256,1))
    float w[HID];
#pragma unroll
    for (int j = 0; j < HID; j += 4) {
        const float4 v = *reinterpret_cast<const float4*>(&Whh[row * HID + j]);
        w[j] = v.x; w[j + 1] = v.y; w[j + 2] = v.z; w[j + 3] = v.w;
    }
    float wi[NIN];
#pragma unroll
    for (int i = 0; i < NIN; ++i) wi[i] = Wih[row * NIN + i];
    const float bias = bih[row] + bhh[row];

    // replicated lane-distributed state
    float h = h0[lane];
    float c = c0[lane];

    __syncthreads();

#define STEP(T, BUF)                                                          \
    {                                                                         \
        const float* xt = &x_s[(T) * NIN];                                    \
        float a0 = bias, a1 = 0.f, a2 = 0.f, a3 = 0.f;                        \
        a0 = fmaf(wi[0], xt[0], a0);                                          \
        a1 = fmaf(wi[1], xt[1], a1);                                          \
        a2 = fmaf(wi[2], xt[2], a2);                                          \
        a3 = fmaf(wi[3], xt[3], a3);                                          \
        a0 = fmaf(wi[4], xt[4], a0);                                          \
        _Pragma("unroll")                                                     \
        for (int j = 0; j < HID; j += 4) {                                    \
            a0 = fmaf(w[j + 0], bcast(h, j + 0), a0);                         \
            a1 = fmaf(w[j + 1], bcast(h, j + 1), a1);                         \
            a2 = fmaf(w[j + 2], bcast(h, j + 2), a2);                         \
            a3 = fmaf(w[j + 3], bcast(h, j + 3), a3);                         \
        }                                                                     \
        const float pre = (a0 + a1) + (a2 + a3);                              \
        const float act = (wv == 2) ? fast_tanh(pre) : fast_sigmoid(pre);     \
        g_s[BUF][row] = act;                                                  \
        __syncthreads();                                                      \
        const float ig = g_s[BUF][lane];                                      \
        const float fg = g_s[BUF][HID + lane];                                \
        const float gg = g_s[BUF][2 * HID + lane];                            \
        const float og = g_s[BUF][3 * HID + lane];                            \
        c = fmaf(fg, c, ig * gg);                                             \
        h = og * fast_tanh(c);                                                \
        if (wv == 0) hseq[(T)][lane] = h;                                     \
    }

#pragma unroll 1
    for (int t = 0; t < TSEQ; t += 2) {
        STEP(t, 0);
        STEP(t + 1, 1);
    }
#undef STEP

    __syncthreads();

    // ---- linear1: flat[t*96 + k] = b1[k] + W1[k,:] . hseq[t,:] ----
    // Wave wv owns t in [wv*24, wv*24+24). Lane holds W1 row kA=lane in regs,
    // and row kB=64+lane for lanes < 32.
    {
        float w1a[HID];
#pragma unroll
        for (int j = 0; j < HID; j += 4) {
            const float4 v = *reinterpret_cast<const float4*>(&W1[lane * HID + j]);
            w1a[j] = v.x; w1a[j + 1] = v.y; w1a[j + 2] = v.z; w1a[j + 3] = v.w;
        }
        const int kB = 64 + (lane & 31);           // valid only for lane < 32
        float w1b[HID];
#pragma unroll
        for (int j = 0; j < HID; j += 4) {
            const float4 v = *reinterpret_cast<const float4*>(&W1[kB * HID + j]);
            w1b[j] = v.x; w1b[j + 1] = v.y; w1b[j + 2] = v.z; w1b[j + 3] = v.w;
        }
        const float b1a = b1[lane];
        const float b1b = b1[kB];

#pragma unroll 1
        for (int tt = 0; tt < TSEQ / 4; ++tt) {
            const int t = wv * (TSEQ / 4) + tt;
            const float hreg = hseq[t][lane];
            float sa0 = 0.f, sa1 = 0.f, sb0 = 0.f, sb1 = 0.f;
#pragma unroll
            for (int j = 0; j < HID; j += 2) {
                const float hj0 = bcast(hreg, j);
                const float hj1 = bcast(hreg, j + 1);
                sa0 = fmaf(w1a[j], hj0, sa0);
                sa1 = fmaf(w1a[j + 1], hj1, sa1);
                sb0 = fmaf(w1b[j], hj0, sb0);
                sb1 = fmaf(w1b[j + 1], hj1, sb1);
            }
            flat_out[t * NOUT + lane] = b1a + (sa0 + sa1);
            if (lane < 32) flat_out[t * NOUT + kB] = b1b + (sb0 + sb1);
        }
    }
}

// Kernel 2: out[o] = b2[o] + W2[o,:] . flat   (96 blocks, one output each)
__global__ __launch_bounds__(256) void gemv_final_kernel(
    const float* __restrict__ W2,    // (96, 9216)
    const float* __restrict__ b2,    // (96)
    const float* __restrict__ flat,  // (9216)
    float* __restrict__ out)         // (96)
{
    const int o = blockIdx.x;
    const int tid = threadIdx.x;
    const float* __restrict__ row = &W2[o * FLATN];

    float s = 0.f;
#pragma unroll 4
    for (int j = tid; j < FLATN; j += 256) {
        s += row[j] * flat[j];
    }

#pragma unroll
    for (int off = 32; off > 0; off >>= 1) s += __shfl_down(s, off, 64);

    __shared__ float partial[4];
    if ((tid & 63) == 0) partial[tid >> 6] = s;
    __syncthreads();
    if (tid == 0) {
        out[o] = b2[o] + ((partial[0] + partial[1]) + (partial[2] + partial[3]));
    }
}

extern "C" void kernel_launch(void* const* d_in, const int* in_sizes, int n_in,
                              void* d_out, int out_size, void* d_ws, size_t ws_size,
                              hipStream_t stream) {
    const float* x   = (const float*)d_in[0];
    const float* h0  = (const float*)d_in[1];
    const float* c0  = (const float*)d_in[2];
    const float* Wih = (const float*)d_in[3];
    const float* Whh = (const float*)d_in[4];
    const float* bih = (const float*)d_in[5];
    const float* bhh = (const float*)d_in[6];
    const float* W1  = (const float*)d_in[7];
    const float* b1  = (const float*)d_in[8];
    const float* W2  = (const float*)d_in[9];
    const float* b2  = (const float*)d_in[10];

    float* out  = (float*)d_out;
    float* flat = (float*)d_ws;   // 9216 floats

    lstm_fused<<<1, 256, 0, stream>>>(x, h0, c0, Wih, Whh, bih, bhh, W1, b1, flat);
    gemv_final_kernel<<<NOUT, 256, 0, stream>>>(W2, b2, flat, out);
}